// Round 9
// baseline (76.826 us; speedup 1.0000x reference)
//
#include <hip/hip_runtime.h>

#define NB    8
#define NIN   512
#define TOUT  4096
#define ND    384
#define J4    (ND / 4)     // 96 float4 per row
#define TROWS 16           // output rows per gather block
#define BLK   256          // gather threads per block (4 waves)

typedef float f32x4 __attribute__((ext_vector_type(4)));

// Kernel 1: scan ds[b] (one block per batch, one thread per token) and
// scatter the owning token index into owner[b*TOUT + t] (-1 = empty).
// No binary search: intervals are disjoint, each thread writes <=7 slots.
__global__ __launch_bounds__(NIN) void build_owner(const int* __restrict__ ds,
                                                   int* __restrict__ owner) {
    const int b   = blockIdx.x;
    const int tid = threadIdx.x;            // 0..511, one token each
    __shared__ int wsum[NIN / 64];          // 8 wave totals

    const int d = ds[b * NIN + tid];
    int p = d;
    const int lane = tid & 63;
    const int wid  = tid >> 6;
    #pragma unroll
    for (int off = 1; off < 64; off <<= 1) {
        int v = __shfl_up(p, off, 64);
        if (lane >= off) p += v;
    }
    if (lane == 63) wsum[wid] = p;

    // init owner map to -1 (8 writes/thread), ordered vs scatter by barrier
    int* ob = owner + b * TOUT;
    #pragma unroll
    for (int t = tid; t < TOUT; t += NIN) ob[t] = -1;
    __syncthreads();

    int acc = 0;
    #pragma unroll
    for (int w = 0; w < NIN / 64; ++w)
        if (w < wid) acc += wsum[w];
    p += acc;                               // inclusive cumsum
    int right = p < TOUT ? p : TOUT;
    for (int t = p - d; t < right; ++t) ob[t] = tid;
}

// Kernel 2: pure gather stream — no LDS, no barriers, no preamble.
// owner load (L2-hot) -> xs load (L2-hot, XCD-pinned batch) -> store.
// 2048 blocks = 8/CU = 32 waves/CU; 6 preloaded iters keep loads in flight.
__global__ __launch_bounds__(BLK) void gather(const f32x4* __restrict__ xs,
                                              const int* __restrict__ owner,
                                              f32x4* __restrict__ out) {
    const int b       = blockIdx.x & 7;             // batch -> XCD pin
    const int rowbase = (blockIdx.x >> 3) * TROWS;  // first output frame
    const int tid     = threadIdx.x;

    const int*   ob   = owner + b * TOUT + rowbase;
    const f32x4* xsb  = xs + (size_t)b * NIN * J4;
    f32x4*       outb = out + ((size_t)b * TOUT + rowbase) * J4;

    constexpr int ITER = TROWS * J4 / BLK;          // 6
    int   o[ITER];
    f32x4 v[ITER];
    #pragma unroll
    for (int k = 0; k < ITER; ++k)
        o[k] = ob[(k * BLK + tid) / J4];
    #pragma unroll
    for (int k = 0; k < ITER; ++k) {
        const int g = k * BLK + tid;                // 0..1535
        const int j = g - (g / J4) * J4;            // float4 within row
        v[k] = (f32x4)(0.f);
        if (o[k] >= 0) v[k] = xsb[o[k] * J4 + j];
    }
    #pragma unroll
    for (int k = 0; k < ITER; ++k)
        outb[k * BLK + tid] = v[k];
}

extern "C" void kernel_launch(void* const* d_in, const int* in_sizes, int n_in,
                              void* d_out, int out_size, void* d_ws, size_t ws_size,
                              hipStream_t stream) {
    const float* xs = (const float*)d_in[0];   // (8, 512, 384) f32
    const int*   ds = (const int*)d_in[1];     // (8, 512) int
    float* out = (float*)d_out;                // (8, 4096, 384) f32
    int* owner = (int*)d_ws;                   // NB*TOUT ints = 128 KB

    build_owner<<<NB, NIN, 0, stream>>>(ds, owner);
    gather<<<(TOUT / TROWS) * NB, BLK, 0, stream>>>((const f32x4*)xs, owner,
                                                    (f32x4*)out);
}